// Round 12
// baseline (252.490 us; speedup 1.0000x reference)
//
#include <hip/hip_runtime.h>

// ConvTranspose2d(64->64, k=3, s=2, p=1, out_pad=1) + bias + clip(0, 0.5)
// x: (32,64,128,128) f32, w: (64ci,64co,3,3) f32, b: (64) f32 -> out: (32,64,256,256) f32
//
// MFMA path, r8 numerics (verified): 9-tap parity decomposition,
// mfma_f32_32x32x16_f16, A=w-frag (rows=co), B=x-frag (cols=pixel),
// x split hi/lo f16 (2 products), w single RTN f16.
//
// Round-12: ZERO-LDS / ZERO-BARRIER dataflow. The x-fragment's lane dim is
// 32 consecutive pixels at fixed ci == 128B coalesced rows of global x, so
// fragments are built straight from global into registers (8 dword loads +
// f16 hi/lo convert). No staging, no ds ops, no __syncthreads anywhere:
// every wave is an independent dataflow; TLP (12 waves/CU) hides latency.
// This removes the 2-phase stage+vmcnt+barrier critical path that pinned
// rounds 8-11 at ~205 us.

#define CIN 64
#define COUT 64
#define HI 128
#define WI 128
#define HO 256
#define WO 256
#define HW (HI*WI)

typedef __attribute__((ext_vector_type(8))) _Float16 half8;
typedef __attribute__((ext_vector_type(16))) float f32x16;

__device__ __forceinline__ unsigned short f2h(float v) {
    _Float16 h = (_Float16)v;                       // v_cvt_f16_f32 (RTN)
    return __builtin_bit_cast(unsigned short, h);
}

// ---- prep: wfrag[frag=(tap*4+ks)*2+ct][lane64][j8] f16 (verified r8) ----
__global__ void prep_wfrag(const float* __restrict__ w, unsigned short* __restrict__ wf) {
    int idx = blockIdx.x * 256 + threadIdx.x;
    if (idx >= 72 * 64) return;
    int lane = idx & 63;
    int frag = idx >> 6;
    int ct  = frag & 1;
    int ks  = (frag >> 1) & 3;
    int tap = frag >> 3;
    int co  = ct * 32 + (lane & 31);
    unsigned int packed[4];
    #pragma unroll
    for (int jp = 0; jp < 4; ++jp) {
        unsigned short h2[2];
        #pragma unroll
        for (int e = 0; e < 2; ++e) {
            int j = jp * 2 + e;
            int ci = ks * 16 + (lane >> 5) * 8 + j;
            h2[e] = f2h(w[(ci * COUT + co) * 9 + tap]);
        }
        packed[jp] = (unsigned)h2[0] | ((unsigned)h2[1] << 16);
    }
    ((uint4*)wf)[idx] = make_uint4(packed[0], packed[1], packed[2], packed[3]);
}

__global__ __launch_bounds__(256, 3) void convt_mfma_kernel(
    const float* __restrict__ x,
    const unsigned short* __restrict__ wf,
    const float* __restrict__ bias,
    float* __restrict__ out)
{
    const int n    = blockIdx.z;
    const int i_in = blockIdx.y * 2;    // owned input rows i_in, i_in+1 (+1 halo row)
    const int j0   = blockIdx.x * 32;   // owned input cols j0..j0+31 (+1 halo col)

    const int tid = threadIdx.x;
    const int l   = tid & 63;
    const int wid = tid >> 6;
    const int ct  = wid & 1;            // co tile (32 co per wave)
    const int rp  = wid >> 1;           // owned input row within block (0,1)
    const int jj  = l & 31;
    const int ch  = l >> 5;             // ci-half selector

    const float* xn = x + (size_t)n * CIN * HW;

    f32x16 acc[2][2];   // [dh][dw]
    #pragma unroll
    for (int a = 0; a < 2; ++a)
        #pragma unroll
        for (int b = 0; b < 2; ++b)
            #pragma unroll
            for (int e = 0; e < 16; ++e) acc[a][b][e] = 0.0f;

    // build one x-fragment (hi+lo) directly from global:
    // 8 dword loads (each 128B-coalesced across lanes 0-31 / 32-63) + RTN split
    #define BUILD_XF(KS, R, S)                                                       \
        half8 xh, xl;                                                                \
        {                                                                            \
            const int gi = i_in + rp + (R);                                          \
            const int gj = j0 + jj + (S);                                            \
            const bool ok = (gi < HI) && (gj < WI);                                  \
            const float* bp = xn + ((size_t)((KS) * 16 + ch * 8) * HI + gi) * WI + gj;\
            _Pragma("unroll")                                                        \
            for (int k = 0; k < 8; ++k) {                                            \
                float v = ok ? bp[(size_t)k * HW] : 0.0f;                            \
                _Float16 h = (_Float16)v;                                            \
                xh[k] = h;                                                           \
                xl[k] = (_Float16)(v - (float)h);                                    \
            }                                                                        \
        }

    #define DO_TAP(t, dh, dw)                                                        \
        {                                                                            \
            f32x16 a = acc[dh][dw];                                                  \
            a = __builtin_amdgcn_mfma_f32_32x32x16_f16(wr[t], xh, a, 0, 0, 0);       \
            a = __builtin_amdgcn_mfma_f32_32x32x16_f16(wr[t], xl, a, 0, 0, 0);       \
            acc[dh][dw] = a;                                                         \
        }

    #pragma unroll
    for (int ks = 0; ks < 4; ++ks) {
        half8 wr[9];
        #pragma unroll
        for (int t = 0; t < 9; ++t)
            wr[t] = *(const half8*)&wf[(size_t)(((t * 4 + ks) * 2 + ct) * 512) + l * 8];

        { BUILD_XF(ks, 1, 1) DO_TAP(0, 1, 1) }                                   // t0
        { BUILD_XF(ks, 1, 0) DO_TAP(1, 1, 0) DO_TAP(2, 1, 1) }                   // t1,t2
        { BUILD_XF(ks, 0, 1) DO_TAP(3, 0, 1) DO_TAP(6, 1, 1) }                   // t3,t6
        { BUILD_XF(ks, 0, 0) DO_TAP(4, 0, 0) DO_TAP(5, 0, 1)
                             DO_TAP(7, 1, 0) DO_TAP(8, 1, 1) }                   // t4,5,7,8
    }
    #undef DO_TAP
    #undef BUILD_XF

    // ---- epilogue: bias + clamp; lane = pixel -> coalesced dwordx2 stores ----
    float bco[16];
    #pragma unroll
    for (int rg = 0; rg < 16; ++rg)
        bco[rg] = bias[ct * 32 + (rg & 3) + 8 * (rg >> 2) + 4 * ch];

    float* outn = out + (size_t)n * COUT * HO * WO;
    const int ow0 = 2 * (j0 + jj);
    #pragma unroll
    for (int dh = 0; dh < 2; ++dh) {
        const int oh = 2 * (i_in + rp) + dh;
        #pragma unroll
        for (int rg = 0; rg < 16; ++rg) {
            const int co = ct * 32 + (rg & 3) + 8 * (rg >> 2) + 4 * ch;
            float v0 = acc[dh][0][rg] + bco[rg];
            float v1 = acc[dh][1][rg] + bco[rg];
            v0 = fminf(fmaxf(v0, 0.f), 0.5f);
            v1 = fminf(fmaxf(v1, 0.f), 0.5f);
            *(float2*)&outn[((size_t)co * HO + oh) * WO + ow0] = make_float2(v0, v1);
        }
    }
}

// ---------------- fallback (no-workspace): fp32 VALU kernel ----------------
#define TILE_I 4
#define TILE_J 16
#define HALO_I (TILE_I + 1)
#define HALO_J (TILE_J + 1)
#define XS_CSTRIDE 20
#define XS_RSTRIDE (HALO_I * XS_CSTRIDE)
#define XS_FLOATS (CIN * XS_RSTRIDE)

struct Regs { float wk[9]; float xa[2][HALO_J]; };

__device__ __forceinline__ void load_ci_fb(int ci, const float* __restrict__ wsrc,
                                           const float* xs, int warp, int lane, Regs& R) {
    #pragma unroll
    for (int k = 0; k < 9; ++k) R.wk[k] = wsrc[(ci * COUT + lane) * 9 + k];
    const float* xr = xs + ci * XS_RSTRIDE + warp * XS_CSTRIDE;
    #pragma unroll
    for (int rr = 0; rr < 2; ++rr) {
        const float4* p4 = reinterpret_cast<const float4*>(xr + rr * XS_CSTRIDE);
        #pragma unroll
        for (int q = 0; q < 4; ++q) {
            float4 v = p4[q];
            R.xa[rr][4*q+0] = v.x; R.xa[rr][4*q+1] = v.y;
            R.xa[rr][4*q+2] = v.z; R.xa[rr][4*q+3] = v.w;
        }
        R.xa[rr][16] = xr[rr * XS_CSTRIDE + 16];
    }
}

__device__ __forceinline__ void do_fma_fb(const Regs& R, float (&acc)[TILE_J][4]) {
    #pragma unroll
    for (int p = 0; p < TILE_J; ++p) {
        const float x00 = R.xa[0][p], x01 = R.xa[0][p+1];
        const float x10 = R.xa[1][p], x11 = R.xa[1][p+1];
        acc[p][0] += x00 * R.wk[4];
        acc[p][1] += x00 * R.wk[5]; acc[p][1] += x01 * R.wk[3];
        acc[p][2] += x00 * R.wk[7]; acc[p][2] += x10 * R.wk[1];
        acc[p][3] += x00 * R.wk[8]; acc[p][3] += x01 * R.wk[6];
        acc[p][3] += x10 * R.wk[2]; acc[p][3] += x11 * R.wk[0];
    }
}

__device__ __forceinline__ int es_slot_fb(int co, int oh, int g) {
    return co * 64 + oh * 8 + (g ^ (co & 7) ^ oh);
}

__global__ __launch_bounds__(256, 2) void convt_fallback_kernel(
    const float* __restrict__ x, const float* __restrict__ wsrc,
    const float* __restrict__ bias, float* __restrict__ out) {
    __shared__ __align__(16) float xs[XS_FLOATS];
    const int n = blockIdx.z, i0 = blockIdx.y * TILE_I, j0 = blockIdx.x * TILE_J;
    const float* xnf = x + (size_t)n * CIN * HI * WI;
    for (int f = threadIdx.x; f < CIN * HALO_I * HALO_J; f += 256) {
        int ci = f / (HALO_I * HALO_J);
        int rem = f - ci * (HALO_I * HALO_J);
        int r = rem / HALO_J, c = rem - r * HALO_J;
        int gi = i0 + r, gj = j0 + c;
        float v = 0.0f;
        if (gi < HI && gj < WI) v = xnf[(ci * HI + gi) * WI + gj];
        xs[ci * XS_RSTRIDE + r * XS_CSTRIDE + c] = v;
    }
    __syncthreads();
    const int warp = threadIdx.x >> 6, lane = threadIdx.x & 63;
    const float bcf = bias[lane];
    float acc[TILE_J][4];
    #pragma unroll
    for (int p = 0; p < TILE_J; ++p)
        #pragma unroll
        for (int q = 0; q < 4; ++q) acc[p][q] = 0.0f;
    Regs A, B1;
    load_ci_fb(0, wsrc, xs, warp, lane, A);
    #pragma unroll 1
    for (int ci = 0; ci < CIN; ci += 2) {
        load_ci_fb(ci + 1, wsrc, xs, warp, lane, B1);
        do_fma_fb(A, acc);
        int cin = (ci + 2 < CIN) ? ci + 2 : CIN - 1;
        load_ci_fb(cin, wsrc, xs, warp, lane, A);
        do_fma_fb(B1, acc);
    }
    float* outn = out + (size_t)n * COUT * HO * WO;
    const int ohb = 2 * i0, owb = 2 * j0;
    __syncthreads();
    float* es = xs;
    #pragma unroll 1
    for (int chunk = 0; chunk < 4; ++chunk) {
        const int c0 = chunk * 16;
        if ((lane & 48) == c0) {
            const int col = lane & 15;
            #pragma unroll
            for (int p = 0; p < TILE_J; ++p)
                #pragma unroll
                for (int q = 0; q < 4; ++q) {
                    const int ohl = warp * 2 + (q >> 1);
                    const int ow = 2 * p + (q & 1);
                    float v = acc[p][q] + bcf;
                    v = fminf(fmaxf(v, 0.0f), 0.5f);
                    es[es_slot_fb(col, ohl, ow >> 2) * 4 + (ow & 3)] = v;
                }
        }
        __syncthreads();
        {
            const int co_l = threadIdx.x >> 4;
            const int oh_l = (threadIdx.x & 15) >> 1;
            const int half = threadIdx.x & 1;
            float* dst = &outn[((size_t)(c0 + co_l) * HO + (ohb + oh_l)) * WO + owb + half * 16];
            #pragma unroll
            for (int qq = 0; qq < 4; ++qq) {
                const int g = half * 4 + qq;
                float4 v = *reinterpret_cast<const float4*>(&es[es_slot_fb(co_l, oh_l, g) * 4]);
                *reinterpret_cast<float4*>(dst + qq * 4) = v;
            }
        }
        __syncthreads();
    }
}

extern "C" void kernel_launch(void* const* d_in, const int* in_sizes, int n_in,
                              void* d_out, int out_size, void* d_ws, size_t ws_size,
                              hipStream_t stream) {
    const float* x = (const float*)d_in[0];
    const float* w = (const float*)d_in[1];
    const float* b = (const float*)d_in[2];
    float* out = (float*)d_out;
    const int B = in_sizes[0] / (CIN * HI * WI);  // 32

    const size_t wf_bytes = (size_t)72 * 64 * 8 * sizeof(unsigned short); // 73728
    if (ws_size >= wf_bytes) {
        unsigned short* wfrag = (unsigned short*)d_ws;
        prep_wfrag<<<18, 256, 0, stream>>>(w, wfrag);
        dim3 grid(WI / 32, HI / 2, B);            // (4, 64, 32) — r8 mapping
        convt_mfma_kernel<<<grid, 256, 0, stream>>>(x, wfrag, b, out);
    } else {
        dim3 grid(WI / TILE_J, HI / TILE_I, B);   // (8, 32, 32)
        convt_fallback_kernel<<<grid, 256, 0, stream>>>(x, w, b, out);
    }
}